// Round 1
// baseline (5344.056 us; speedup 1.0000x reference)
//
#include <hip/hip_runtime.h>
#include <cstdint>

#define NTAP 27
#define CH 32
static constexpr int N_LOW = 16384;
static constexpr int M_ALL = 131072;

// ---------------- init / gt_mask normalization ----------------

__global__ void k_init(int* cnt) {
    int t = threadIdx.x;
    if (t < 64) cnt[t] = 0;
}

// Disambiguate gt_mask storage: u8 bool, int32, or f32.
// flagA (cnt[32]): any nonzero byte at pos%4!=0 within first M bytes.
// flagB (cnt[33]): any byte value > 1.
// u8  : flagA=1, flagB=0.  int32: flagA=0.  f32: flagA=1, flagB=1 (0x80/0x3F bytes).
__global__ __launch_bounds__(256) void k_gt_detect(const unsigned char* __restrict__ p, int* flags) {
    int i = blockIdx.x * 256 + threadIdx.x;
    bool a = false, b = false;
    if (i < M_ALL) {
        unsigned char v = p[i];
        a = ((i & 3) != 0) && (v != 0);
        b = (v > 1);
    }
    unsigned long long ba = __ballot(a);
    unsigned long long bb = __ballot(b);
    if ((threadIdx.x & 63) == 0) {
        if (ba) atomicOr(&flags[32], 1);
        if (bb) atomicOr(&flags[33], 1);
    }
}

__global__ __launch_bounds__(256) void k_gt_norm(const unsigned char* __restrict__ p,
                                                 unsigned char* __restrict__ gt8,
                                                 const int* __restrict__ flags) {
    int i = blockIdx.x * 256 + threadIdx.x;
    if (i >= M_ALL) return;
    bool u8 = (flags[32] != 0) && (flags[33] == 0);
    unsigned char v;
    if (u8) v = (p[i] != 0) ? 1 : 0;
    else    v = (((const int*)p)[i] != 0) ? 1 : 0;   // works for int32 and f32 bit patterns
    gt8[i] = v;
}

// ---------------- low-grid first conv (Cin=1) ----------------

__global__ __launch_bounds__(256) void k_conv_low0(const float* __restrict__ x,
                                                   const int* __restrict__ nbr,
                                                   const float* __restrict__ w0,   // [27][1][32]
                                                   const float* __restrict__ b0,   // [32]
                                                   float* __restrict__ out) {      // [N][32]
    int g = blockIdx.x * 256 + threadIdx.x;           // grid covers N_LOW*32 exactly
    int n = g >> 5, co = g & 31;
    float acc = b0[co];
    const int* nr = nbr + n * NTAP;
    for (int k = 0; k < NTAP; ++k) {
        int j = nr[k];
        if (j >= 0) acc += x[j] * w0[k * CH + co];
    }
    out[g] = fmaxf(acc, 0.f);
}

// ---------------- generic 27-tap conv, C=32 -> C=32 ----------------
// Block = 256 threads = 32 rows x 8 cout-quads. Per tap: stage W[k] (4KB) and the
// 32 gathered input rows into LDS (stride 36 floats -> conflict-free b128 reads),
// then 128 fmac per thread into acc[4].

template<int RELU, int ADD, int USE_LIST>
__global__ __launch_bounds__(256) void k_conv27(
    const float* __restrict__ f,
    float* __restrict__ out,
    const float* __restrict__ addsrc,
    const float* __restrict__ W,        // [27][32][32]
    const float* __restrict__ bias,     // [32]
    const int* __restrict__ nbr,        // fixed: nbr_low [N][27]; list: nbrS [count][27] (validity folded)
    const int* __restrict__ list,       // list mode: compacted index -> dense row
    const int* __restrict__ d_count,
    int fixedN)
{
    __shared__ float wbuf[CH * CH];     // 1024 floats
    __shared__ float fbuf[32 * 36];     // 32 rows, padded stride 36
    const int nrows = USE_LIST ? d_count[0] : fixedN;
    const int nchunks = (nrows + 31) >> 5;
    const int t = threadIdx.x;
    const int lrow = t >> 3;
    const int sub = t & 7;
    for (int chunk = blockIdx.x; chunk < nchunks; chunk += gridDim.x) {
        const int myrow = (chunk << 5) + lrow;
        const bool act = myrow < nrows;
        float acc0 = 0.f, acc1 = 0.f, acc2 = 0.f, acc3 = 0.f;
        const int* nrow = nbr + (long)myrow * NTAP;
        #pragma unroll 1
        for (int k = 0; k < NTAP; ++k) {
            __syncthreads();
            ((float4*)wbuf)[t] = ((const float4*)W)[k * 256 + t];
            float4 fv = make_float4(0.f, 0.f, 0.f, 0.f);
            if (act) {
                int j = nrow[k];
                if (j >= 0) fv = ((const float4*)(f + (long)j * CH))[sub];
            }
            *((float4*)(fbuf + lrow * 36 + sub * 4)) = fv;
            __syncthreads();
            if (act) {
                const float* fr = fbuf + lrow * 36;
                #pragma unroll
                for (int c4 = 0; c4 < 8; ++c4) {
                    float4 fq = *((const float4*)(fr + c4 * 4));
                    const float* wp = wbuf + c4 * 4 * CH + sub * 4;
                    float4 w0 = *((const float4*)(wp + 0 * CH));
                    float4 w1 = *((const float4*)(wp + 1 * CH));
                    float4 w2 = *((const float4*)(wp + 2 * CH));
                    float4 w3 = *((const float4*)(wp + 3 * CH));
                    acc0 += fq.x * w0.x; acc1 += fq.x * w0.y; acc2 += fq.x * w0.z; acc3 += fq.x * w0.w;
                    acc0 += fq.y * w1.x; acc1 += fq.y * w1.y; acc2 += fq.y * w1.z; acc3 += fq.y * w1.w;
                    acc0 += fq.z * w2.x; acc1 += fq.z * w2.y; acc2 += fq.z * w2.z; acc3 += fq.z * w2.w;
                    acc0 += fq.w * w3.x; acc1 += fq.w * w3.y; acc2 += fq.w * w3.z; acc3 += fq.w * w3.w;
                }
            }
        }
        if (act) {
            const int m = USE_LIST ? list[myrow] : myrow;
            const float4 b = ((const float4*)bias)[sub];
            float4 r;
            r.x = acc0 + b.x; r.y = acc1 + b.y; r.z = acc2 + b.z; r.w = acc3 + b.w;
            if (ADD) {
                float4 a = ((const float4*)(addsrc + (long)m * CH))[sub];
                r.x += a.x; r.y += a.y; r.z += a.z; r.w += a.w;
            }
            if (RELU) {
                r.x = fmaxf(r.x, 0.f); r.y = fmaxf(r.y, 0.f);
                r.z = fmaxf(r.z, 0.f); r.w = fmaxf(r.w, 0.f);
            }
            ((float4*)(out + (long)m * CH))[sub] = r;
        }
    }
}

// ---------------- generative transpose conv k2 s2 ----------------
// feats[m = p*8+o][d] = sum_c h[p][c] * wt[o][c][d] + bt[d]

__global__ __launch_bounds__(256) void k_tconv(
    const float* __restrict__ h,        // [N][32]
    const float* __restrict__ wt,       // [8][32][32]
    const float* __restrict__ bt,       // [32]
    float* __restrict__ out)            // [M][32]
{
    __shared__ float wl[8 * 1060];      // per-o stride 1060 -> banks o*4 apart, conflict-free
    for (int i = threadIdx.x; i < 8 * CH * CH; i += 256) {
        wl[(i >> 10) * 1060 + (i & 1023)] = wt[i];
    }
    __syncthreads();
    const int m = blockIdx.x * 256 + threadIdx.x;     // grid covers M exactly
    const int p = m >> 3, o = m & 7;
    float hr[CH], acc[CH];
    #pragma unroll
    for (int c4 = 0; c4 < 8; ++c4) {
        float4 v = ((const float4*)(h + (long)p * CH))[c4];
        hr[c4*4+0] = v.x; hr[c4*4+1] = v.y; hr[c4*4+2] = v.z; hr[c4*4+3] = v.w;
        float4 b = ((const float4*)bt)[c4];
        acc[c4*4+0] = b.x; acc[c4*4+1] = b.y; acc[c4*4+2] = b.z; acc[c4*4+3] = b.w;
    }
    const float* wb = wl + o * 1060;
    #pragma unroll
    for (int ci = 0; ci < CH; ++ci) {
        float hv = hr[ci];
        #pragma unroll
        for (int c4 = 0; c4 < 8; ++c4) {
            float4 w = *((const float4*)(wb + ci * CH + c4 * 4));
            acc[c4*4+0] += hv * w.x; acc[c4*4+1] += hv * w.y;
            acc[c4*4+2] += hv * w.z; acc[c4*4+3] += hv * w.w;
        }
    }
    #pragma unroll
    for (int c4 = 0; c4 < 8; ++c4) {
        ((float4*)(out + (long)m * CH))[c4] =
            make_float4(acc[c4*4+0], acc[c4*4+1], acc[c4*4+2], acc[c4*4+3]);
    }
}

// ---------------- stage prep / neighbor folding ----------------

__global__ __launch_bounds__(256) void k_prep0(unsigned char* __restrict__ valid,
                                               int* __restrict__ list, int* cnt) {
    int m = blockIdx.x * 256 + threadIdx.x;
    if (m >= M_ALL) return;
    int v = ((m & 7) == 0);              // STAGE_ORDER[0] == 0
    valid[m] = (unsigned char)v;
    if (v) { int i = atomicAdd(cnt, 1); list[i] = m; }
}

__global__ __launch_bounds__(256) void k_prep(const unsigned char* __restrict__ gt8,
                                              unsigned char* __restrict__ valid,
                                              const float* __restrict__ HS,
                                              const float* __restrict__ fu,
                                              float* __restrict__ F,
                                              int* __restrict__ list, int* cnt, int so) {
    int m = blockIdx.x * 256 + threadIdx.x;
    if (m >= M_ALL) return;
    int ov = valid[m] & gt8[m];
    int sl = ((m & 7) == so);
    int nv = ov | sl;
    valid[m] = (unsigned char)nv;
    if (nv) {
        const float4* src = (const float4*)((ov ? HS : fu) + (long)m * CH);
        float4* dst = (float4*)(F + (long)m * CH);
        #pragma unroll
        for (int i = 0; i < 8; ++i) dst[i] = src[i];
        int i = atomicAdd(cnt, 1); list[i] = m;
    }
}

__global__ __launch_bounds__(256) void k_fold(const unsigned char* __restrict__ valid,
                                              const int* __restrict__ nbr_u,
                                              const int* __restrict__ list,
                                              const int* __restrict__ cnt,
                                              int* __restrict__ nbrS) {
    int i = blockIdx.x * 256 + threadIdx.x;
    if (i >= cnt[0] || i >= M_ALL) return;
    int m = list[i];
    const int* src = nbr_u + (long)m * NTAP;
    int* dst = nbrS + (long)i * NTAP;
    #pragma unroll
    for (int k = 0; k < NTAP; ++k) {
        int j = src[k];
        dst[k] = (j >= 0 && valid[j]) ? j : -1;
    }
}

// ---------------- classifier (writes a full [M] plane) ----------------

__global__ __launch_bounds__(256) void k_classifier(
    const float* __restrict__ HS,
    const float* __restrict__ cw0, const float* __restrict__ cb0,
    const float* __restrict__ cw1, const float* __restrict__ cb1,
    const float* __restrict__ cw2, const float* __restrict__ cb2,
    float* __restrict__ outp, int so)
{
    __shared__ float w0[1024], w1[1024], w2[32], b0[32], b1[32];
    for (int i = threadIdx.x; i < 1024; i += 256) { w0[i] = cw0[i]; w1[i] = cw1[i]; }
    if (threadIdx.x < 32) {
        w2[threadIdx.x] = cw2[threadIdx.x];
        b0[threadIdx.x] = cb0[threadIdx.x];
        b1[threadIdx.x] = cb1[threadIdx.x];
    }
    __syncthreads();
    const int m = blockIdx.x * 256 + threadIdx.x;
    if (m >= M_ALL) return;
    if ((m & 7) != so) { outp[m] = 0.f; return; }
    float in[CH], h0[CH], h1[CH];
    #pragma unroll
    for (int c4 = 0; c4 < 8; ++c4) {
        float4 v = ((const float4*)(HS + (long)m * CH))[c4];
        in[c4*4+0] = v.x; in[c4*4+1] = v.y; in[c4*4+2] = v.z; in[c4*4+3] = v.w;
    }
    #pragma unroll
    for (int c = 0; c < CH; ++c) h0[c] = b0[c];
    #pragma unroll
    for (int ci = 0; ci < CH; ++ci) {
        float v = in[ci];
        #pragma unroll
        for (int c4 = 0; c4 < 8; ++c4) {
            float4 w = *((const float4*)(w0 + ci * CH + c4 * 4));
            h0[c4*4+0] += v * w.x; h0[c4*4+1] += v * w.y;
            h0[c4*4+2] += v * w.z; h0[c4*4+3] += v * w.w;
        }
    }
    #pragma unroll
    for (int c = 0; c < CH; ++c) { h0[c] = fmaxf(h0[c], 0.f); h1[c] = b1[c]; }
    #pragma unroll
    for (int ci = 0; ci < CH; ++ci) {
        float v = h0[ci];
        #pragma unroll
        for (int c4 = 0; c4 < 8; ++c4) {
            float4 w = *((const float4*)(w1 + ci * CH + c4 * 4));
            h1[c4*4+0] += v * w.x; h1[c4*4+1] += v * w.y;
            h1[c4*4+2] += v * w.z; h1[c4*4+3] += v * w.w;
        }
    }
    float o = cb2[0];
    #pragma unroll
    for (int ci = 0; ci < CH; ++ci) o += fmaxf(h1[ci], 0.f) * w2[ci];
    outp[m] = o;
}

// ---------------- host orchestration ----------------

extern "C" void kernel_launch(void* const* d_in, const int* in_sizes, int n_in,
                              void* d_out, int out_size, void* d_ws, size_t ws_size,
                              hipStream_t stream)
{
    (void)in_sizes; (void)n_in; (void)out_size; (void)ws_size;
    const float* x_low  = (const float*)d_in[0];
    const float* bi_w0  = (const float*)d_in[1];
    const float* bi_b0  = (const float*)d_in[2];
    const float* bi_w   = (const float*)d_in[3];   // [7][27][32][32]
    const float* bi_b   = (const float*)d_in[4];   // [7][32]
    const float* wt     = (const float*)d_in[5];
    const float* bt     = (const float*)d_in[6];
    const float* sw     = (const float*)d_in[7];   // [8][8][27][32][32]
    const float* sb     = (const float*)d_in[8];   // [8][8][32]
    const float* cw0    = (const float*)d_in[9];
    const float* cb0    = (const float*)d_in[10];
    const float* cw1    = (const float*)d_in[11];
    const float* cb1    = (const float*)d_in[12];
    const float* cw2    = (const float*)d_in[13];
    const float* cb2    = (const float*)d_in[14];
    const int* nbr_low  = (const int*)d_in[15];
    const int* nbr_u    = (const int*)d_in[16];
    const unsigned char* gtraw = (const unsigned char*)d_in[18];
    float* out = (float*)d_out;

    char* w = (char*)d_ws;
    size_t off = 0;
    auto carve = [&](size_t bytes) -> void* {
        void* p = w + off;
        off += (bytes + 255) & ~(size_t)255;
        return p;
    };
    float* feats = (float*)carve((size_t)M_ALL * CH * 4);
    float* A     = (float*)carve((size_t)M_ALL * CH * 4);
    float* X     = (float*)carve((size_t)M_ALL * CH * 4);
    float* HS    = (float*)carve((size_t)M_ALL * CH * 4);
    int* nbrS    = (int*)carve((size_t)M_ALL * NTAP * 4);
    int* list    = (int*)carve((size_t)M_ALL * 4);
    unsigned char* valid = (unsigned char*)carve(M_ALL);
    unsigned char* gt8   = (unsigned char*)carve(M_ALL);
    int* cnt     = (int*)carve(64 * 4);

    const size_t WL = 27648;  // 27*32*32

    k_init<<<1, 64, 0, stream>>>(cnt);
    k_gt_detect<<<512, 256, 0, stream>>>(gtraw, cnt);
    k_gt_norm<<<512, 256, 0, stream>>>(gtraw, gt8, cnt);

    // ---- low-resolution block (stride-2 kernel map, all rows valid) ----
    k_conv_low0<<<(N_LOW * CH) / 256, 256, 0, stream>>>(x_low, nbr_low, bi_w0, bi_b0, A);
    k_conv27<1,0,0><<<1024,256,0,stream>>>(A, X, nullptr, bi_w + 0*WL, bi_b + 0*32, nbr_low, nullptr, nullptr, N_LOW);
    k_conv27<0,1,0><<<1024,256,0,stream>>>(X, A, A,       bi_w + 1*WL, bi_b + 1*32, nbr_low, nullptr, nullptr, N_LOW);
    k_conv27<1,0,0><<<1024,256,0,stream>>>(A, X, nullptr, bi_w + 2*WL, bi_b + 2*32, nbr_low, nullptr, nullptr, N_LOW);
    k_conv27<0,1,0><<<1024,256,0,stream>>>(X, A, A,       bi_w + 3*WL, bi_b + 3*32, nbr_low, nullptr, nullptr, N_LOW);
    k_conv27<1,0,0><<<1024,256,0,stream>>>(A, X, nullptr, bi_w + 4*WL, bi_b + 4*32, nbr_low, nullptr, nullptr, N_LOW);
    k_conv27<0,1,0><<<1024,256,0,stream>>>(X, A, A,       bi_w + 5*WL, bi_b + 5*32, nbr_low, nullptr, nullptr, N_LOW);
    k_conv27<0,0,0><<<1024,256,0,stream>>>(A, X, nullptr, bi_w + 6*WL, bi_b + 6*32, nbr_low, nullptr, nullptr, N_LOW);
    k_tconv<<<512, 256, 0, stream>>>(X, wt, bt, feats);

    // ---- 8 generative stages ----
    static const int order[8] = {0, 7, 1, 6, 5, 2, 3, 4};
    for (int s = 0; s < 8; ++s) {
        const int so = order[s];
        if (s == 0) k_prep0<<<512,256,0,stream>>>(valid, list, cnt + 0);
        else        k_prep <<<512,256,0,stream>>>(gt8, valid, HS, feats, X, list, cnt + s, so);
        k_fold<<<512,256,0,stream>>>(valid, nbr_u, list, cnt + s, nbrS);

        const float* sws = sw + (size_t)s * 8 * WL;
        const float* sbs = sb + (size_t)s * 8 * 32;
        const float* F0  = (s == 0) ? feats : X;
        k_conv27<1,0,1><<<1024,256,0,stream>>>(F0, A, nullptr, sws + 0*WL, sbs + 0*32, nbrS, list, cnt + s, 0);
        k_conv27<1,0,1><<<1024,256,0,stream>>>(A,  X, nullptr, sws + 1*WL, sbs + 1*32, nbrS, list, cnt + s, 0);
        k_conv27<0,1,1><<<1024,256,0,stream>>>(X,  A, A,       sws + 2*WL, sbs + 2*32, nbrS, list, cnt + s, 0);
        k_conv27<1,0,1><<<1024,256,0,stream>>>(A,  X, nullptr, sws + 3*WL, sbs + 3*32, nbrS, list, cnt + s, 0);
        k_conv27<0,1,1><<<1024,256,0,stream>>>(X,  A, A,       sws + 4*WL, sbs + 4*32, nbrS, list, cnt + s, 0);
        k_conv27<1,0,1><<<1024,256,0,stream>>>(A,  X, nullptr, sws + 5*WL, sbs + 5*32, nbrS, list, cnt + s, 0);
        k_conv27<0,1,1><<<1024,256,0,stream>>>(X,  A, A,       sws + 6*WL, sbs + 6*32, nbrS, list, cnt + s, 0);
        k_conv27<0,0,1><<<1024,256,0,stream>>>(A, HS, nullptr, sws + 7*WL, sbs + 7*32, nbrS, list, cnt + s, 0);

        k_classifier<<<512,256,0,stream>>>(HS, cw0, cb0, cw1, cb1, cw2, cb2,
                                           out + (size_t)s * M_ALL, so);
    }
}

// Round 3
// 3001.826 us; speedup vs baseline: 1.7803x; 1.7803x over previous
//
#include <hip/hip_runtime.h>
#include <cstdint>

#define NTAP 27
#define CH 32
static constexpr int N_LOW = 16384;
static constexpr int M_ALL = 131072;
static constexpr int NCHMAX = 2048;   // hard bound: M_ALL/64 chunks

// ---------------- init / gt_mask normalization ----------------

__global__ void k_init(int* cnt) {
    int t = threadIdx.x;
    if (t < 64) cnt[t] = 0;
    if (t == 0) cnt[8] = N_LOW;     // low-map row count
}

__global__ __launch_bounds__(256) void k_gt_detect(const unsigned char* __restrict__ p, int* flags) {
    int i = blockIdx.x * 256 + threadIdx.x;
    bool a = false, b = false;
    if (i < M_ALL) {
        unsigned char v = p[i];
        a = ((i & 3) != 0) && (v != 0);
        b = (v > 1);
    }
    unsigned long long ba = __ballot(a);
    unsigned long long bb = __ballot(b);
    if ((threadIdx.x & 63) == 0) {
        if (ba) atomicOr(&flags[32], 1);
        if (bb) atomicOr(&flags[33], 1);
    }
}

__global__ __launch_bounds__(256) void k_gt_norm(const unsigned char* __restrict__ p,
                                                 unsigned char* __restrict__ gt8,
                                                 const int* __restrict__ flags) {
    int i = blockIdx.x * 256 + threadIdx.x;
    if (i >= M_ALL) return;
    bool u8 = (flags[32] != 0) && (flags[33] == 0);
    unsigned char v;
    if (u8) v = (p[i] != 0) ? 1 : 0;
    else    v = (((const int*)p)[i] != 0) ? 1 : 0;
    gt8[i] = v;
}

__global__ __launch_bounds__(256) void k_iota(int* list) {
    int i = blockIdx.x * 256 + threadIdx.x;
    if (i < N_LOW) list[i] = i;
}

// ---------------- low-grid first conv (Cin=1) ----------------

__global__ __launch_bounds__(256) void k_conv_low0(const float* __restrict__ x,
                                                   const int* __restrict__ nbr,
                                                   const float* __restrict__ w0,
                                                   const float* __restrict__ b0,
                                                   float* __restrict__ out) {
    int g = blockIdx.x * 256 + threadIdx.x;
    int n = g >> 5, co = g & 31;
    float acc = b0[co];
    const int* nr = nbr + n * NTAP;
    for (int k = 0; k < NTAP; ++k) {
        int j = nr[k];
        if (j >= 0) acc += x[j] * w0[k * CH + co];
    }
    out[g] = fmaxf(acc, 0.f);
}

// ---------------- ordered compaction (count / scan / emit) ----------------

template<int FIRST>
__global__ __launch_bounds__(256) void k_vcount(unsigned char* __restrict__ valid,
                                                const unsigned char* __restrict__ gt8,
                                                const float* __restrict__ HS,
                                                const float* __restrict__ feats,
                                                float* __restrict__ F,
                                                int* __restrict__ bcnt, int so) {
    int m = blockIdx.x * 256 + threadIdx.x;
    int v;
    if (FIRST) {
        v = ((m & 7) == 0);
    } else {
        int ov = valid[m] & gt8[m];
        int sl = ((m & 7) == so);
        v = ov | sl;
        if (v) {
            const float4* src = (const float4*)((ov ? HS : feats) + (long)m * CH);
            float4* dst = (float4*)(F + (long)m * CH);
            #pragma unroll
            for (int i = 0; i < 8; ++i) dst[i] = src[i];
        }
    }
    valid[m] = (unsigned char)v;
    __shared__ int red[4];
    unsigned long long b = __ballot(v != 0);
    if ((threadIdx.x & 63) == 0) red[threadIdx.x >> 6] = __popcll(b);
    __syncthreads();
    if (threadIdx.x == 0) bcnt[blockIdx.x] = red[0] + red[1] + red[2] + red[3];
}

__global__ void k_scan512(const int* __restrict__ bcnt, int* __restrict__ boff,
                          int* __restrict__ cnt_out) {
    __shared__ int s[512];
    int t = threadIdx.x;
    int mine = bcnt[t];
    s[t] = mine;
    __syncthreads();
    for (int d = 1; d < 512; d <<= 1) {
        int v = (t >= d) ? s[t - d] : 0;
        __syncthreads();
        s[t] += v;
        __syncthreads();
    }
    boff[t] = s[t] - mine;
    if (t == 511) cnt_out[0] = s[511];
}

__global__ __launch_bounds__(256) void k_emit(const unsigned char* __restrict__ valid,
                                              const int* __restrict__ boff,
                                              int* __restrict__ list) {
    int m = blockIdx.x * 256 + threadIdx.x;
    int v = valid[m];
    __shared__ int wof[4];
    unsigned long long b = __ballot(v != 0);
    int lane = threadIdx.x & 63, w = threadIdx.x >> 6;
    int rank = __popcll(b & ((1ull << lane) - 1ull));
    if (lane == 0) wof[w] = __popcll(b);
    __syncthreads();
    int pre = 0;
    for (int i = 0; i < w; ++i) pre += wof[i];
    if (v) list[boff[blockIdx.x] + pre + rank] = m;
}

// ---------------- pair-list build per (chunk, tap) ----------------
// pent[(c*27+k)*64 + slot] = (lrow<<24) | j   (row unique within (c,k))

template<int VAL>
__global__ __launch_bounds__(256) void k_pairs(const int* __restrict__ nbr,
                                               const int* __restrict__ list,
                                               const int* __restrict__ d_count,
                                               const unsigned char* __restrict__ valid,
                                               int* __restrict__ pcnt,
                                               unsigned int* __restrict__ pent) {
    const int count = d_count[0];
    for (int i = blockIdx.x * 256 + threadIdx.x; i < count; i += gridDim.x * 256) {
        int m = list[i];
        int c = i >> 6, lrow = i & 63;
        const int* nr = nbr + (long)m * NTAP;
        #pragma unroll 1
        for (int k = 0; k < NTAP; ++k) {
            int j = nr[k];
            if (j < 0) continue;
            if (VAL && !valid[j]) continue;
            int slot = atomicAdd(&pcnt[c * NTAP + k], 1);
            if (slot < 64)
                pent[(((long)(c * NTAP + k)) << 6) | slot] = ((unsigned)lrow << 24) | (unsigned)j;
        }
    }
}

// ---------------- pair-compacted conv: 4 waves, wave-private taps+acc ----------------

template<int RELU, int ADD>
__global__ __launch_bounds__(256) void k_convp(
    const float* __restrict__ f,
    float* __restrict__ out,
    const float* __restrict__ addsrc,
    const float* __restrict__ W,        // [27][32][32]
    const float* __restrict__ bias,     // [32]
    const int* __restrict__ list,
    const int* __restrict__ d_count,
    const int* __restrict__ pcnt,
    const unsigned int* __restrict__ pent)
{
    __shared__ float acc[4 * 64 * 36];   // wave-private planes, stride-36 padded
    __shared__ float wb[4 * 1024];       // wave-private W[k]
    __shared__ float fb[4 * 16 * 36];    // wave-private staged rows (2 per slot)
    const int count = d_count[0];
    const int nch = (count + 63) >> 6;
    const int c = blockIdx.x;
    if (c >= nch) return;
    const int t = threadIdx.x;
    const int wave = t >> 6, lane = t & 63;
    const int slot = lane >> 3, coq = lane & 7;
    for (int i = t; i < 4 * 64 * 36; i += 256) acc[i] = 0.f;
    __syncthreads();
    float* accw = acc + wave * (64 * 36);
    float* wbw = wb + wave * 1024;
    float* fbw = fb + wave * (16 * 36);
    const int base_ck = c * NTAP;

    for (int k = wave; k < NTAP; k += 4) {
        const int L = pcnt[base_ck + k];
        if (L == 0) continue;
        // stage W[k] (wave-local, contiguous)
        const float4* Wg = (const float4*)(W + (long)k * 1024);
        #pragma unroll
        for (int r = 0; r < 4; ++r) {
            float4 v = Wg[lane + 64 * r];
            *((float4*)(wbw + (lane + 64 * r) * 4)) = v;
        }
        const unsigned int* pk = pent + (((long)(base_ck + k)) << 6);
        for (int bse = 0; bse < L; bse += 16) {
            const int e0 = bse + slot, e1 = bse + 8 + slot;
            const bool a0 = e0 < L, a1 = e1 < L;
            const unsigned u0 = a0 ? pk[e0] : 0u;
            const unsigned u1 = a1 ? pk[e1] : 0u;
            float4 f0 = make_float4(0.f, 0.f, 0.f, 0.f), f1 = f0;
            if (a0) f0 = ((const float4*)(f + (long)(u0 & 0xFFFFFFu) * CH))[coq];
            if (a1) f1 = ((const float4*)(f + (long)(u1 & 0xFFFFFFu) * CH))[coq];
            *((float4*)(fbw + slot * 72 + coq * 4)) = f0;
            *((float4*)(fbw + slot * 72 + 36 + coq * 4)) = f1;
            asm volatile("s_waitcnt lgkmcnt(0)" ::: "memory");
            __builtin_amdgcn_sched_barrier(0);
            float r00 = 0.f, r01 = 0.f, r02 = 0.f, r03 = 0.f;
            float r10 = 0.f, r11 = 0.f, r12 = 0.f, r13 = 0.f;
            #pragma unroll
            for (int c4 = 0; c4 < 8; ++c4) {
                float4 q0 = *((const float4*)(fbw + slot * 72 + c4 * 4));
                float4 q1 = *((const float4*)(fbw + slot * 72 + 36 + c4 * 4));
                const float* wp = wbw + c4 * 128 + coq * 4;
                float4 w0 = *((const float4*)(wp));
                float4 w1 = *((const float4*)(wp + 32));
                float4 w2 = *((const float4*)(wp + 64));
                float4 w3 = *((const float4*)(wp + 96));
                r00 += q0.x * w0.x; r01 += q0.x * w0.y; r02 += q0.x * w0.z; r03 += q0.x * w0.w;
                r00 += q0.y * w1.x; r01 += q0.y * w1.y; r02 += q0.y * w1.z; r03 += q0.y * w1.w;
                r00 += q0.z * w2.x; r01 += q0.z * w2.y; r02 += q0.z * w2.z; r03 += q0.z * w2.w;
                r00 += q0.w * w3.x; r01 += q0.w * w3.y; r02 += q0.w * w3.z; r03 += q0.w * w3.w;
                r10 += q1.x * w0.x; r11 += q1.x * w0.y; r12 += q1.x * w0.z; r13 += q1.x * w0.w;
                r10 += q1.y * w1.x; r11 += q1.y * w1.y; r12 += q1.y * w1.z; r13 += q1.y * w1.w;
                r10 += q1.z * w2.x; r11 += q1.z * w2.y; r12 += q1.z * w2.z; r13 += q1.z * w2.w;
                r10 += q1.w * w3.x; r11 += q1.w * w3.y; r12 += q1.w * w3.z; r13 += q1.w * w3.w;
            }
            if (a0) {
                float4* ap = (float4*)(accw + (int)(u0 >> 24) * 36 + coq * 4);
                float4 av = *ap;
                av.x += r00; av.y += r01; av.z += r02; av.w += r03;
                *ap = av;
            }
            if (a1) {
                float4* ap = (float4*)(accw + (int)(u1 >> 24) * 36 + coq * 4);
                float4 av = *ap;
                av.x += r10; av.y += r11; av.z += r12; av.w += r13;
                *ap = av;
            }
        }
    }
    __syncthreads();
    // reduce 4 wave planes + epilogue
    for (int cell = t; cell < 512; cell += 256) {
        int r = cell >> 3, q = cell & 7;
        int gi = (c << 6) + r;
        if (gi < count) {
            const int ro = r * 36 + q * 4;
            float4 s0 = *((const float4*)(acc + 0 * 2304 + ro));
            float4 s1 = *((const float4*)(acc + 1 * 2304 + ro));
            float4 s2 = *((const float4*)(acc + 2 * 2304 + ro));
            float4 s3 = *((const float4*)(acc + 3 * 2304 + ro));
            float4 b = ((const float4*)bias)[q];
            float4 o;
            o.x = s0.x + s1.x + s2.x + s3.x + b.x;
            o.y = s0.y + s1.y + s2.y + s3.y + b.y;
            o.z = s0.z + s1.z + s2.z + s3.z + b.z;
            o.w = s0.w + s1.w + s2.w + s3.w + b.w;
            int m = list[gi];
            if (ADD) {
                float4 a = ((const float4*)(addsrc + (long)m * CH))[q];
                o.x += a.x; o.y += a.y; o.z += a.z; o.w += a.w;
            }
            if (RELU) {
                o.x = fmaxf(o.x, 0.f); o.y = fmaxf(o.y, 0.f);
                o.z = fmaxf(o.z, 0.f); o.w = fmaxf(o.w, 0.f);
            }
            ((float4*)(out + (long)m * CH))[q] = o;
        }
    }
}

// ---------------- generative transpose conv k2 s2 ----------------

__global__ __launch_bounds__(256) void k_tconv(
    const float* __restrict__ h,
    const float* __restrict__ wt,
    const float* __restrict__ bt,
    float* __restrict__ out)
{
    __shared__ float wl[8 * 1060];
    for (int i = threadIdx.x; i < 8 * CH * CH; i += 256) {
        wl[(i >> 10) * 1060 + (i & 1023)] = wt[i];
    }
    __syncthreads();
    const int m = blockIdx.x * 256 + threadIdx.x;
    const int p = m >> 3, o = m & 7;
    float hr[CH], acc[CH];
    #pragma unroll
    for (int c4 = 0; c4 < 8; ++c4) {
        float4 v = ((const float4*)(h + (long)p * CH))[c4];
        hr[c4*4+0] = v.x; hr[c4*4+1] = v.y; hr[c4*4+2] = v.z; hr[c4*4+3] = v.w;
        float4 b = ((const float4*)bt)[c4];
        acc[c4*4+0] = b.x; acc[c4*4+1] = b.y; acc[c4*4+2] = b.z; acc[c4*4+3] = b.w;
    }
    const float* wb = wl + o * 1060;
    #pragma unroll
    for (int ci = 0; ci < CH; ++ci) {
        float hv = hr[ci];
        #pragma unroll
        for (int c4 = 0; c4 < 8; ++c4) {
            float4 w = *((const float4*)(wb + ci * CH + c4 * 4));
            acc[c4*4+0] += hv * w.x; acc[c4*4+1] += hv * w.y;
            acc[c4*4+2] += hv * w.z; acc[c4*4+3] += hv * w.w;
        }
    }
    #pragma unroll
    for (int c4 = 0; c4 < 8; ++c4) {
        ((float4*)(out + (long)m * CH))[c4] =
            make_float4(acc[c4*4+0], acc[c4*4+1], acc[c4*4+2], acc[c4*4+3]);
    }
}

// ---------------- classifier ----------------

__global__ __launch_bounds__(256) void k_classifier(
    const float* __restrict__ HS,
    const float* __restrict__ cw0, const float* __restrict__ cb0,
    const float* __restrict__ cw1, const float* __restrict__ cb1,
    const float* __restrict__ cw2, const float* __restrict__ cb2,
    float* __restrict__ outp, int so)
{
    __shared__ float w0[1024], w1[1024], w2[32], b0[32], b1[32];
    for (int i = threadIdx.x; i < 1024; i += 256) { w0[i] = cw0[i]; w1[i] = cw1[i]; }
    if (threadIdx.x < 32) {
        w2[threadIdx.x] = cw2[threadIdx.x];
        b0[threadIdx.x] = cb0[threadIdx.x];
        b1[threadIdx.x] = cb1[threadIdx.x];
    }
    __syncthreads();
    const int m = blockIdx.x * 256 + threadIdx.x;
    if (m >= M_ALL) return;
    if ((m & 7) != so) { outp[m] = 0.f; return; }
    float in[CH], h0[CH], h1[CH];
    #pragma unroll
    for (int c4 = 0; c4 < 8; ++c4) {
        float4 v = ((const float4*)(HS + (long)m * CH))[c4];
        in[c4*4+0] = v.x; in[c4*4+1] = v.y; in[c4*4+2] = v.z; in[c4*4+3] = v.w;
    }
    #pragma unroll
    for (int c = 0; c < CH; ++c) h0[c] = b0[c];
    #pragma unroll
    for (int ci = 0; ci < CH; ++ci) {
        float v = in[ci];
        #pragma unroll
        for (int c4 = 0; c4 < 8; ++c4) {
            float4 w = *((const float4*)(w0 + ci * CH + c4 * 4));
            h0[c4*4+0] += v * w.x; h0[c4*4+1] += v * w.y;
            h0[c4*4+2] += v * w.z; h0[c4*4+3] += v * w.w;
        }
    }
    #pragma unroll
    for (int c = 0; c < CH; ++c) { h0[c] = fmaxf(h0[c], 0.f); h1[c] = b1[c]; }
    #pragma unroll
    for (int ci = 0; ci < CH; ++ci) {
        float v = h0[ci];
        #pragma unroll
        for (int c4 = 0; c4 < 8; ++c4) {
            float4 w = *((const float4*)(w1 + ci * CH + c4 * 4));
            h1[c4*4+0] += v * w.x; h1[c4*4+1] += v * w.y;
            h1[c4*4+2] += v * w.z; h1[c4*4+3] += v * w.w;
        }
    }
    float o = cb2[0];
    #pragma unroll
    for (int ci = 0; ci < CH; ++ci) o += fmaxf(h1[ci], 0.f) * w2[ci];
    outp[m] = o;
}

// ---------------- host orchestration ----------------

extern "C" void kernel_launch(void* const* d_in, const int* in_sizes, int n_in,
                              void* d_out, int out_size, void* d_ws, size_t ws_size,
                              hipStream_t stream)
{
    (void)in_sizes; (void)n_in; (void)out_size; (void)ws_size;
    const float* x_low  = (const float*)d_in[0];
    const float* bi_w0  = (const float*)d_in[1];
    const float* bi_b0  = (const float*)d_in[2];
    const float* bi_w   = (const float*)d_in[3];
    const float* bi_b   = (const float*)d_in[4];
    const float* wt     = (const float*)d_in[5];
    const float* bt     = (const float*)d_in[6];
    const float* sw     = (const float*)d_in[7];
    const float* sb     = (const float*)d_in[8];
    const float* cw0    = (const float*)d_in[9];
    const float* cb0    = (const float*)d_in[10];
    const float* cw1    = (const float*)d_in[11];
    const float* cb1    = (const float*)d_in[12];
    const float* cw2    = (const float*)d_in[13];
    const float* cb2    = (const float*)d_in[14];
    const int* nbr_low  = (const int*)d_in[15];
    const int* nbr_u    = (const int*)d_in[16];
    const unsigned char* gtraw = (const unsigned char*)d_in[18];
    float* out = (float*)d_out;

    char* w = (char*)d_ws;
    size_t off = 0;
    auto carve = [&](size_t bytes) -> void* {
        void* p = w + off;
        off += (bytes + 255) & ~(size_t)255;
        return p;
    };
    float* feats = (float*)carve((size_t)M_ALL * CH * 4);
    float* A     = (float*)carve((size_t)M_ALL * CH * 4);
    float* X     = (float*)carve((size_t)M_ALL * CH * 4);
    float* HS    = (float*)carve((size_t)M_ALL * CH * 4);
    unsigned int* pent = (unsigned int*)carve((size_t)NCHMAX * NTAP * 64 * 4);
    int* pcnt    = (int*)carve((size_t)NCHMAX * NTAP * 4);
    int* list    = (int*)carve((size_t)M_ALL * 4);
    int* list_low= (int*)carve((size_t)N_LOW * 4);
    int* bcnt    = (int*)carve(512 * 4);
    int* boff    = (int*)carve(512 * 4);
    unsigned char* valid = (unsigned char*)carve(M_ALL);
    unsigned char* gt8   = (unsigned char*)carve(M_ALL);
    int* cnt     = (int*)carve(64 * 4);

    const size_t WL = 27648;       // 27*32*32
    const size_t PCNT_B = (size_t)NCHMAX * NTAP * 4;

    k_init<<<1, 64, 0, stream>>>(cnt);
    k_gt_detect<<<512, 256, 0, stream>>>(gtraw, cnt);
    k_gt_norm<<<512, 256, 0, stream>>>(gtraw, gt8, cnt);
    k_iota<<<64, 256, 0, stream>>>(list_low);

    // ---- low-resolution block (exactly 256 chunks) ----
    k_conv_low0<<<(N_LOW * CH) / 256, 256, 0, stream>>>(x_low, nbr_low, bi_w0, bi_b0, A);
    hipMemsetAsync(pcnt, 0, PCNT_B, stream);
    k_pairs<0><<<256, 256, 0, stream>>>(nbr_low, list_low, cnt + 8, nullptr, pcnt, pent);
    const int GL = 256;
    k_convp<1,0><<<GL,256,0,stream>>>(A, X, nullptr, bi_w + 0*WL, bi_b + 0*32, list_low, cnt + 8, pcnt, pent);
    k_convp<0,1><<<GL,256,0,stream>>>(X, A, A,       bi_w + 1*WL, bi_b + 1*32, list_low, cnt + 8, pcnt, pent);
    k_convp<1,0><<<GL,256,0,stream>>>(A, X, nullptr, bi_w + 2*WL, bi_b + 2*32, list_low, cnt + 8, pcnt, pent);
    k_convp<0,1><<<GL,256,0,stream>>>(X, A, A,       bi_w + 3*WL, bi_b + 3*32, list_low, cnt + 8, pcnt, pent);
    k_convp<1,0><<<GL,256,0,stream>>>(A, X, nullptr, bi_w + 4*WL, bi_b + 4*32, list_low, cnt + 8, pcnt, pent);
    k_convp<0,1><<<GL,256,0,stream>>>(X, A, A,       bi_w + 5*WL, bi_b + 5*32, list_low, cnt + 8, pcnt, pent);
    k_convp<0,0><<<GL,256,0,stream>>>(A, X, nullptr, bi_w + 6*WL, bi_b + 6*32, list_low, cnt + 8, pcnt, pent);
    k_tconv<<<512, 256, 0, stream>>>(X, wt, bt, feats);

    // ---- 8 generative stages ----
    static const int order[8] = {0, 7, 1, 6, 5, 2, 3, 4};
    for (int s = 0; s < 8; ++s) {
        const int so = order[s];
        if (s == 0) k_vcount<1><<<512,256,0,stream>>>(valid, gt8, nullptr, nullptr, nullptr, bcnt, so);
        else        k_vcount<0><<<512,256,0,stream>>>(valid, gt8, HS, feats, X, bcnt, so);
        k_scan512<<<1, 512, 0, stream>>>(bcnt, boff, cnt + s);
        k_emit<<<512, 256, 0, stream>>>(valid, boff, list);
        hipMemsetAsync(pcnt, 0, PCNT_B, stream);
        k_pairs<1><<<256, 256, 0, stream>>>(nbr_u, list, cnt + s, valid, pcnt, pent);

        // stage-s valid set is a subset of the union of the first s+1 octant
        // slices -> count <= 16384*(s+1) -> chunks <= 256*(s+1)
        int GS = 256 * (s + 1);
        if (GS > NCHMAX) GS = NCHMAX;
        const float* sws = sw + (size_t)s * 8 * WL;
        const float* sbs = sb + (size_t)s * 8 * 32;
        const float* F0  = (s == 0) ? feats : X;
        k_convp<1,0><<<GS,256,0,stream>>>(F0, A, nullptr, sws + 0*WL, sbs + 0*32, list, cnt + s, pcnt, pent);
        k_convp<1,0><<<GS,256,0,stream>>>(A,  X, nullptr, sws + 1*WL, sbs + 1*32, list, cnt + s, pcnt, pent);
        k_convp<0,1><<<GS,256,0,stream>>>(X,  A, A,       sws + 2*WL, sbs + 2*32, list, cnt + s, pcnt, pent);
        k_convp<1,0><<<GS,256,0,stream>>>(A,  X, nullptr, sws + 3*WL, sbs + 3*32, list, cnt + s, pcnt, pent);
        k_convp<0,1><<<GS,256,0,stream>>>(X,  A, A,       sws + 4*WL, sbs + 4*32, list, cnt + s, pcnt, pent);
        k_convp<1,0><<<GS,256,0,stream>>>(A,  X, nullptr, sws + 5*WL, sbs + 5*32, list, cnt + s, pcnt, pent);
        k_convp<0,1><<<GS,256,0,stream>>>(X,  A, A,       sws + 6*WL, sbs + 6*32, list, cnt + s, pcnt, pent);
        k_convp<0,0><<<GS,256,0,stream>>>(A, HS, nullptr, sws + 7*WL, sbs + 7*32, list, cnt + s, pcnt, pent);

        k_classifier<<<512,256,0,stream>>>(HS, cw0, cb0, cw1, cb1, cw2, cb2,
                                           out + (size_t)s * M_ALL, so);
    }
}

// Round 4
// 2396.100 us; speedup vs baseline: 2.2303x; 1.2528x over previous
//
#include <hip/hip_runtime.h>
#include <cstdint>

#define NTAP 27
#define CH 32
static constexpr int N_LOW = 16384;
static constexpr int M_ALL = 131072;
static constexpr int NCHMAX = 2048;   // hard bound: M_ALL/64 chunks

// ---------------- init / gt_mask normalization ----------------

__global__ void k_init(int* cnt) {
    int t = threadIdx.x;
    if (t < 64) cnt[t] = 0;
    if (t == 0) cnt[8] = N_LOW;     // low-map row count
}

__global__ __launch_bounds__(256) void k_gt_detect(const unsigned char* __restrict__ p, int* flags) {
    int i = blockIdx.x * 256 + threadIdx.x;
    bool a = false, b = false;
    if (i < M_ALL) {
        unsigned char v = p[i];
        a = ((i & 3) != 0) && (v != 0);
        b = (v > 1);
    }
    unsigned long long ba = __ballot(a);
    unsigned long long bb = __ballot(b);
    if ((threadIdx.x & 63) == 0) {
        if (ba) atomicOr(&flags[32], 1);
        if (bb) atomicOr(&flags[33], 1);
    }
}

__global__ __launch_bounds__(256) void k_gt_norm(const unsigned char* __restrict__ p,
                                                 unsigned char* __restrict__ gt8,
                                                 const int* __restrict__ flags) {
    int i = blockIdx.x * 256 + threadIdx.x;
    if (i >= M_ALL) return;
    bool u8 = (flags[32] != 0) && (flags[33] == 0);
    unsigned char v;
    if (u8) v = (p[i] != 0) ? 1 : 0;
    else    v = (((const int*)p)[i] != 0) ? 1 : 0;
    gt8[i] = v;
}

__global__ __launch_bounds__(256) void k_iota(int* list) {
    int i = blockIdx.x * 256 + threadIdx.x;
    if (i < N_LOW) list[i] = i;
}

// ---------------- low-grid first conv (Cin=1) ----------------

__global__ __launch_bounds__(256) void k_conv_low0(const float* __restrict__ x,
                                                   const int* __restrict__ nbr,
                                                   const float* __restrict__ w0,
                                                   const float* __restrict__ b0,
                                                   float* __restrict__ out) {
    int g = blockIdx.x * 256 + threadIdx.x;
    int n = g >> 5, co = g & 31;
    float acc = b0[co];
    const int* nr = nbr + n * NTAP;
    for (int k = 0; k < NTAP; ++k) {
        int j = nr[k];
        if (j >= 0) acc += x[j] * w0[k * CH + co];
    }
    out[g] = fmaxf(acc, 0.f);
}

// ---------------- ordered compaction (count / scan / emit) ----------------

template<int FIRST>
__global__ __launch_bounds__(256) void k_vcount(unsigned char* __restrict__ valid,
                                                const unsigned char* __restrict__ gt8,
                                                const float* __restrict__ HS,
                                                const float* __restrict__ feats,
                                                float* __restrict__ F,
                                                int* __restrict__ bcnt, int so) {
    int m = blockIdx.x * 256 + threadIdx.x;
    int v;
    if (FIRST) {
        v = ((m & 7) == 0);
    } else {
        int ov = valid[m] & gt8[m];
        int sl = ((m & 7) == so);
        v = ov | sl;
        if (v) {
            const float4* src = (const float4*)((ov ? HS : feats) + (long)m * CH);
            float4* dst = (float4*)(F + (long)m * CH);
            #pragma unroll
            for (int i = 0; i < 8; ++i) dst[i] = src[i];
        }
    }
    valid[m] = (unsigned char)v;
    __shared__ int red[4];
    unsigned long long b = __ballot(v != 0);
    if ((threadIdx.x & 63) == 0) red[threadIdx.x >> 6] = __popcll(b);
    __syncthreads();
    if (threadIdx.x == 0) bcnt[blockIdx.x] = red[0] + red[1] + red[2] + red[3];
}

__global__ void k_scan512(const int* __restrict__ bcnt, int* __restrict__ boff,
                          int* __restrict__ cnt_out) {
    __shared__ int s[512];
    int t = threadIdx.x;
    int mine = bcnt[t];
    s[t] = mine;
    __syncthreads();
    for (int d = 1; d < 512; d <<= 1) {
        int v = (t >= d) ? s[t - d] : 0;
        __syncthreads();
        s[t] += v;
        __syncthreads();
    }
    boff[t] = s[t] - mine;
    if (t == 511) cnt_out[0] = s[511];
}

__global__ __launch_bounds__(256) void k_emit(const unsigned char* __restrict__ valid,
                                              const int* __restrict__ boff,
                                              int* __restrict__ list) {
    int m = blockIdx.x * 256 + threadIdx.x;
    int v = valid[m];
    __shared__ int wof[4];
    unsigned long long b = __ballot(v != 0);
    int lane = threadIdx.x & 63, w = threadIdx.x >> 6;
    int rank = __popcll(b & ((1ull << lane) - 1ull));
    if (lane == 0) wof[w] = __popcll(b);
    __syncthreads();
    int pre = 0;
    for (int i = 0; i < w; ++i) pre += wof[i];
    if (v) list[boff[blockIdx.x] + pre + rank] = m;
}

// ---------------- pair-list build per (chunk, tap): ballot-based, no atomics --------
// pent[(c*27+k)*64 + rank] = (lrow<<24) | j ; pcnt[c*27+k] = popcount.
// One block per chunk; chunk's 64 rows <-> one wave's 64 lanes; waves split taps.

template<int VAL>
__global__ __launch_bounds__(256) void k_pairs2(const int* __restrict__ nbr,
                                                const int* __restrict__ list,
                                                const int* __restrict__ d_count,
                                                const unsigned char* __restrict__ valid,
                                                int* __restrict__ pcnt,
                                                unsigned int* __restrict__ pent) {
    const int count = d_count[0];
    const int nch = (count + 63) >> 6;
    const int c = blockIdx.x;
    if (c >= nch) return;
    const int t = threadIdx.x, wave = t >> 6, lane = t & 63;
    const int gi = (c << 6) + lane;
    const int m = (gi < count) ? list[gi] : -1;
    const int* nr = nbr + (long)m * NTAP;
    for (int k = wave; k < NTAP; k += 4) {
        int j = -1;
        if (m >= 0) {
            j = nr[k];
            if (VAL && j >= 0 && !valid[j]) j = -1;
        }
        unsigned long long mask = __ballot(j >= 0);
        int rank = __popcll(mask & ((1ull << lane) - 1ull));
        if (j >= 0)
            pent[(((long)(c * NTAP + k)) << 6) | rank] = ((unsigned)lane << 24) | (unsigned)j;
        if (lane == 0) pcnt[c * NTAP + k] = __popcll(mask);
    }
}

// ---------------- pair-compacted conv: 4 waves, wave-private taps+acc ----------------
// Software-pipelined: bucket entries preloaded to regs; f-row gathers for batch b+1
// issued before batch b's FMA block (gather latency hides under compute).

template<int RELU, int ADD>
__global__ __launch_bounds__(256) void k_convp(
    const float* __restrict__ f,
    float* __restrict__ out,
    const float* __restrict__ addsrc,
    const float* __restrict__ W,        // [27][32][32]
    const float* __restrict__ bias,     // [32]
    const int* __restrict__ list,
    const int* __restrict__ d_count,
    const int* __restrict__ pcnt,
    const unsigned int* __restrict__ pent)
{
    __shared__ float acc[4 * 64 * 36];   // wave-private planes, stride-36 padded
    __shared__ float wb[4 * 1024];       // wave-private W[k]
    __shared__ float fb[4 * 16 * 36];    // wave-private staged rows (2 per slot)
    const int count = d_count[0];
    const int nch = (count + 63) >> 6;
    const int c = blockIdx.x;
    if (c >= nch) return;
    const int t = threadIdx.x;
    const int wave = t >> 6, lane = t & 63;
    const int slot = lane >> 3, coq = lane & 7;
    for (int i = t; i < 4 * 64 * 36; i += 256) acc[i] = 0.f;
    __syncthreads();
    float* accw = acc + wave * (64 * 36);
    float* wbw = wb + wave * 1024;
    float* fbw = fb + wave * (16 * 36);
    const int base_ck = c * NTAP;

    for (int k = wave; k < NTAP; k += 4) {
        const int L = pcnt[base_ck + k];
        if (L == 0) continue;
        // stage W[k] (wave-local, contiguous)
        const float4* Wg = (const float4*)(W + (long)k * 1024);
        #pragma unroll
        for (int r = 0; r < 4; ++r) {
            float4 v = Wg[lane + 64 * r];
            *((float4*)(wbw + (lane + 64 * r) * 4)) = v;
        }
        const unsigned int* pk = pent + (((long)(base_ck + k)) << 6);
        // preload this slot's entries (batch b uses ent[2b], ent[2b+1])
        unsigned ent[8];
        #pragma unroll
        for (int r = 0; r < 8; ++r) {
            int idx = r * 8 + slot;
            ent[r] = (idx < L) ? pk[idx] : 0xFFFFFFFFu;
        }
        const int nb = (L + 15) >> 4;
        // prefetch batch 0
        unsigned u0 = ent[0], u1 = ent[1];
        float4 g0 = make_float4(0.f, 0.f, 0.f, 0.f), g1 = g0;
        if (u0 != 0xFFFFFFFFu) g0 = ((const float4*)(f + (long)(u0 & 0xFFFFFFu) * CH))[coq];
        if (u1 != 0xFFFFFFFFu) g1 = ((const float4*)(f + (long)(u1 & 0xFFFFFFu) * CH))[coq];
        #pragma unroll
        for (int b = 0; b < 4; ++b) {
            if (b >= nb) break;
            // stage current batch (compiler inserts vmcnt wait on g0/g1)
            *((float4*)(fbw + slot * 72 + coq * 4)) = g0;
            *((float4*)(fbw + slot * 72 + 36 + coq * 4)) = g1;
            // issue next batch's gathers (overlap with FMA below)
            unsigned nu0 = 0xFFFFFFFFu, nu1 = 0xFFFFFFFFu;
            float4 n0 = make_float4(0.f, 0.f, 0.f, 0.f), n1 = n0;
            if (b + 1 < 4 && b + 1 < nb) {
                nu0 = ent[2 * b + 2];
                nu1 = ent[2 * b + 3];
                if (nu0 != 0xFFFFFFFFu) n0 = ((const float4*)(f + (long)(nu0 & 0xFFFFFFu) * CH))[coq];
                if (nu1 != 0xFFFFFFFFu) n1 = ((const float4*)(f + (long)(nu1 & 0xFFFFFFu) * CH))[coq];
            }
            asm volatile("s_waitcnt lgkmcnt(0)" ::: "memory");
            __builtin_amdgcn_sched_barrier(0);
            float r00 = 0.f, r01 = 0.f, r02 = 0.f, r03 = 0.f;
            float r10 = 0.f, r11 = 0.f, r12 = 0.f, r13 = 0.f;
            #pragma unroll
            for (int c4 = 0; c4 < 8; ++c4) {
                float4 q0 = *((const float4*)(fbw + slot * 72 + c4 * 4));
                float4 q1 = *((const float4*)(fbw + slot * 72 + 36 + c4 * 4));
                const float* wp = wbw + c4 * 128 + coq * 4;
                float4 w0 = *((const float4*)(wp));
                float4 w1 = *((const float4*)(wp + 32));
                float4 w2 = *((const float4*)(wp + 64));
                float4 w3 = *((const float4*)(wp + 96));
                r00 += q0.x * w0.x; r01 += q0.x * w0.y; r02 += q0.x * w0.z; r03 += q0.x * w0.w;
                r00 += q0.y * w1.x; r01 += q0.y * w1.y; r02 += q0.y * w1.z; r03 += q0.y * w1.w;
                r00 += q0.z * w2.x; r01 += q0.z * w2.y; r02 += q0.z * w2.z; r03 += q0.z * w2.w;
                r00 += q0.w * w3.x; r01 += q0.w * w3.y; r02 += q0.w * w3.z; r03 += q0.w * w3.w;
                r10 += q1.x * w0.x; r11 += q1.x * w0.y; r12 += q1.x * w0.z; r13 += q1.x * w0.w;
                r10 += q1.y * w1.x; r11 += q1.y * w1.y; r12 += q1.y * w1.z; r13 += q1.y * w1.w;
                r10 += q1.z * w2.x; r11 += q1.z * w2.y; r12 += q1.z * w2.z; r13 += q1.z * w2.w;
                r10 += q1.w * w3.x; r11 += q1.w * w3.y; r12 += q1.w * w3.z; r13 += q1.w * w3.w;
            }
            if (u0 != 0xFFFFFFFFu) {
                float4* ap = (float4*)(accw + (int)(u0 >> 24) * 36 + coq * 4);
                float4 av = *ap;
                av.x += r00; av.y += r01; av.z += r02; av.w += r03;
                *ap = av;
            }
            if (u1 != 0xFFFFFFFFu) {
                float4* ap = (float4*)(accw + (int)(u1 >> 24) * 36 + coq * 4);
                float4 av = *ap;
                av.x += r10; av.y += r11; av.z += r12; av.w += r13;
                *ap = av;
            }
            u0 = nu0; u1 = nu1; g0 = n0; g1 = n1;
        }
    }
    __syncthreads();
    // reduce 4 wave planes + epilogue
    for (int cell = t; cell < 512; cell += 256) {
        int r = cell >> 3, q = cell & 7;
        int gi = (c << 6) + r;
        if (gi < count) {
            const int ro = r * 36 + q * 4;
            float4 s0 = *((const float4*)(acc + 0 * 2304 + ro));
            float4 s1 = *((const float4*)(acc + 1 * 2304 + ro));
            float4 s2 = *((const float4*)(acc + 2 * 2304 + ro));
            float4 s3 = *((const float4*)(acc + 3 * 2304 + ro));
            float4 b = ((const float4*)bias)[q];
            float4 o;
            o.x = s0.x + s1.x + s2.x + s3.x + b.x;
            o.y = s0.y + s1.y + s2.y + s3.y + b.y;
            o.z = s0.z + s1.z + s2.z + s3.z + b.z;
            o.w = s0.w + s1.w + s2.w + s3.w + b.w;
            int m = list[gi];
            if (ADD) {
                float4 a = ((const float4*)(addsrc + (long)m * CH))[q];
                o.x += a.x; o.y += a.y; o.z += a.z; o.w += a.w;
            }
            if (RELU) {
                o.x = fmaxf(o.x, 0.f); o.y = fmaxf(o.y, 0.f);
                o.z = fmaxf(o.z, 0.f); o.w = fmaxf(o.w, 0.f);
            }
            ((float4*)(out + (long)m * CH))[q] = o;
        }
    }
}

// ---------------- generative transpose conv k2 s2 ----------------

__global__ __launch_bounds__(256) void k_tconv(
    const float* __restrict__ h,
    const float* __restrict__ wt,
    const float* __restrict__ bt,
    float* __restrict__ out)
{
    __shared__ float wl[8 * 1060];
    for (int i = threadIdx.x; i < 8 * CH * CH; i += 256) {
        wl[(i >> 10) * 1060 + (i & 1023)] = wt[i];
    }
    __syncthreads();
    const int m = blockIdx.x * 256 + threadIdx.x;
    const int p = m >> 3, o = m & 7;
    float hr[CH], acc[CH];
    #pragma unroll
    for (int c4 = 0; c4 < 8; ++c4) {
        float4 v = ((const float4*)(h + (long)p * CH))[c4];
        hr[c4*4+0] = v.x; hr[c4*4+1] = v.y; hr[c4*4+2] = v.z; hr[c4*4+3] = v.w;
        float4 b = ((const float4*)bt)[c4];
        acc[c4*4+0] = b.x; acc[c4*4+1] = b.y; acc[c4*4+2] = b.z; acc[c4*4+3] = b.w;
    }
    const float* wb = wl + o * 1060;
    #pragma unroll
    for (int ci = 0; ci < CH; ++ci) {
        float hv = hr[ci];
        #pragma unroll
        for (int c4 = 0; c4 < 8; ++c4) {
            float4 w = *((const float4*)(wb + ci * CH + c4 * 4));
            acc[c4*4+0] += hv * w.x; acc[c4*4+1] += hv * w.y;
            acc[c4*4+2] += hv * w.z; acc[c4*4+3] += hv * w.w;
        }
    }
    #pragma unroll
    for (int c4 = 0; c4 < 8; ++c4) {
        ((float4*)(out + (long)m * CH))[c4] =
            make_float4(acc[c4*4+0], acc[c4*4+1], acc[c4*4+2], acc[c4*4+3]);
    }
}

// ---------------- classifier ----------------

__global__ __launch_bounds__(256) void k_classifier(
    const float* __restrict__ HS,
    const float* __restrict__ cw0, const float* __restrict__ cb0,
    const float* __restrict__ cw1, const float* __restrict__ cb1,
    const float* __restrict__ cw2, const float* __restrict__ cb2,
    float* __restrict__ outp, int so)
{
    __shared__ float w0[1024], w1[1024], w2[32], b0[32], b1[32];
    for (int i = threadIdx.x; i < 1024; i += 256) { w0[i] = cw0[i]; w1[i] = cw1[i]; }
    if (threadIdx.x < 32) {
        w2[threadIdx.x] = cw2[threadIdx.x];
        b0[threadIdx.x] = cb0[threadIdx.x];
        b1[threadIdx.x] = cb1[threadIdx.x];
    }
    __syncthreads();
    const int m = blockIdx.x * 256 + threadIdx.x;
    if (m >= M_ALL) return;
    if ((m & 7) != so) { outp[m] = 0.f; return; }
    float in[CH], h0[CH], h1[CH];
    #pragma unroll
    for (int c4 = 0; c4 < 8; ++c4) {
        float4 v = ((const float4*)(HS + (long)m * CH))[c4];
        in[c4*4+0] = v.x; in[c4*4+1] = v.y; in[c4*4+2] = v.z; in[c4*4+3] = v.w;
    }
    #pragma unroll
    for (int c = 0; c < CH; ++c) h0[c] = b0[c];
    #pragma unroll
    for (int ci = 0; ci < CH; ++ci) {
        float v = in[ci];
        #pragma unroll
        for (int c4 = 0; c4 < 8; ++c4) {
            float4 w = *((const float4*)(w0 + ci * CH + c4 * 4));
            h0[c4*4+0] += v * w.x; h0[c4*4+1] += v * w.y;
            h0[c4*4+2] += v * w.z; h0[c4*4+3] += v * w.w;
        }
    }
    #pragma unroll
    for (int c = 0; c < CH; ++c) { h0[c] = fmaxf(h0[c], 0.f); h1[c] = b1[c]; }
    #pragma unroll
    for (int ci = 0; ci < CH; ++ci) {
        float v = h0[ci];
        #pragma unroll
        for (int c4 = 0; c4 < 8; ++c4) {
            float4 w = *((const float4*)(w1 + ci * CH + c4 * 4));
            h1[c4*4+0] += v * w.x; h1[c4*4+1] += v * w.y;
            h1[c4*4+2] += v * w.z; h1[c4*4+3] += v * w.w;
        }
    }
    float o = cb2[0];
    #pragma unroll
    for (int ci = 0; ci < CH; ++ci) o += fmaxf(h1[ci], 0.f) * w2[ci];
    outp[m] = o;
}

// ---------------- host orchestration ----------------

extern "C" void kernel_launch(void* const* d_in, const int* in_sizes, int n_in,
                              void* d_out, int out_size, void* d_ws, size_t ws_size,
                              hipStream_t stream)
{
    (void)in_sizes; (void)n_in; (void)out_size; (void)ws_size;
    const float* x_low  = (const float*)d_in[0];
    const float* bi_w0  = (const float*)d_in[1];
    const float* bi_b0  = (const float*)d_in[2];
    const float* bi_w   = (const float*)d_in[3];
    const float* bi_b   = (const float*)d_in[4];
    const float* wt     = (const float*)d_in[5];
    const float* bt     = (const float*)d_in[6];
    const float* sw     = (const float*)d_in[7];
    const float* sb     = (const float*)d_in[8];
    const float* cw0    = (const float*)d_in[9];
    const float* cb0    = (const float*)d_in[10];
    const float* cw1    = (const float*)d_in[11];
    const float* cb1    = (const float*)d_in[12];
    const float* cw2    = (const float*)d_in[13];
    const float* cb2    = (const float*)d_in[14];
    const int* nbr_low  = (const int*)d_in[15];
    const int* nbr_u    = (const int*)d_in[16];
    const unsigned char* gtraw = (const unsigned char*)d_in[18];
    float* out = (float*)d_out;

    char* w = (char*)d_ws;
    size_t off = 0;
    auto carve = [&](size_t bytes) -> void* {
        void* p = w + off;
        off += (bytes + 255) & ~(size_t)255;
        return p;
    };
    float* feats = (float*)carve((size_t)M_ALL * CH * 4);
    float* A     = (float*)carve((size_t)M_ALL * CH * 4);
    float* X     = (float*)carve((size_t)M_ALL * CH * 4);
    float* HS    = (float*)carve((size_t)M_ALL * CH * 4);
    unsigned int* pent = (unsigned int*)carve((size_t)NCHMAX * NTAP * 64 * 4);
    int* pcnt    = (int*)carve((size_t)NCHMAX * NTAP * 4);
    int* list    = (int*)carve((size_t)M_ALL * 4);
    int* list_low= (int*)carve((size_t)N_LOW * 4);
    int* bcnt    = (int*)carve(512 * 4);
    int* boff    = (int*)carve(512 * 4);
    unsigned char* valid = (unsigned char*)carve(M_ALL);
    unsigned char* gt8   = (unsigned char*)carve(M_ALL);
    int* cnt     = (int*)carve(64 * 4);

    const size_t WL = 27648;       // 27*32*32

    k_init<<<1, 64, 0, stream>>>(cnt);
    k_gt_detect<<<512, 256, 0, stream>>>(gtraw, cnt);
    k_gt_norm<<<512, 256, 0, stream>>>(gtraw, gt8, cnt);
    k_iota<<<64, 256, 0, stream>>>(list_low);

    // ---- low-resolution block (exactly 256 chunks) ----
    k_conv_low0<<<(N_LOW * CH) / 256, 256, 0, stream>>>(x_low, nbr_low, bi_w0, bi_b0, A);
    const int GL = 256;
    k_pairs2<0><<<GL, 256, 0, stream>>>(nbr_low, list_low, cnt + 8, nullptr, pcnt, pent);
    k_convp<1,0><<<GL,256,0,stream>>>(A, X, nullptr, bi_w + 0*WL, bi_b + 0*32, list_low, cnt + 8, pcnt, pent);
    k_convp<0,1><<<GL,256,0,stream>>>(X, A, A,       bi_w + 1*WL, bi_b + 1*32, list_low, cnt + 8, pcnt, pent);
    k_convp<1,0><<<GL,256,0,stream>>>(A, X, nullptr, bi_w + 2*WL, bi_b + 2*32, list_low, cnt + 8, pcnt, pent);
    k_convp<0,1><<<GL,256,0,stream>>>(X, A, A,       bi_w + 3*WL, bi_b + 3*32, list_low, cnt + 8, pcnt, pent);
    k_convp<1,0><<<GL,256,0,stream>>>(A, X, nullptr, bi_w + 4*WL, bi_b + 4*32, list_low, cnt + 8, pcnt, pent);
    k_convp<0,1><<<GL,256,0,stream>>>(X, A, A,       bi_w + 5*WL, bi_b + 5*32, list_low, cnt + 8, pcnt, pent);
    k_convp<0,0><<<GL,256,0,stream>>>(A, X, nullptr, bi_w + 6*WL, bi_b + 6*32, list_low, cnt + 8, pcnt, pent);
    k_tconv<<<512, 256, 0, stream>>>(X, wt, bt, feats);

    // ---- 8 generative stages ----
    static const int order[8] = {0, 7, 1, 6, 5, 2, 3, 4};
    for (int s = 0; s < 8; ++s) {
        const int so = order[s];
        if (s == 0) k_vcount<1><<<512,256,0,stream>>>(valid, gt8, nullptr, nullptr, nullptr, bcnt, so);
        else        k_vcount<0><<<512,256,0,stream>>>(valid, gt8, HS, feats, X, bcnt, so);
        k_scan512<<<1, 512, 0, stream>>>(bcnt, boff, cnt + s);
        k_emit<<<512, 256, 0, stream>>>(valid, boff, list);

        // stage-s valid set is a subset of the union of the first s+1 octant
        // slices -> count <= 16384*(s+1) -> chunks <= 256*(s+1)
        int GS = 256 * (s + 1);
        if (GS > NCHMAX) GS = NCHMAX;
        k_pairs2<1><<<GS, 256, 0, stream>>>(nbr_u, list, cnt + s, valid, pcnt, pent);

        const float* sws = sw + (size_t)s * 8 * WL;
        const float* sbs = sb + (size_t)s * 8 * 32;
        const float* F0  = (s == 0) ? feats : X;
        k_convp<1,0><<<GS,256,0,stream>>>(F0, A, nullptr, sws + 0*WL, sbs + 0*32, list, cnt + s, pcnt, pent);
        k_convp<1,0><<<GS,256,0,stream>>>(A,  X, nullptr, sws + 1*WL, sbs + 1*32, list, cnt + s, pcnt, pent);
        k_convp<0,1><<<GS,256,0,stream>>>(X,  A, A,       sws + 2*WL, sbs + 2*32, list, cnt + s, pcnt, pent);
        k_convp<1,0><<<GS,256,0,stream>>>(A,  X, nullptr, sws + 3*WL, sbs + 3*32, list, cnt + s, pcnt, pent);
        k_convp<0,1><<<GS,256,0,stream>>>(X,  A, A,       sws + 4*WL, sbs + 4*32, list, cnt + s, pcnt, pent);
        k_convp<1,0><<<GS,256,0,stream>>>(A,  X, nullptr, sws + 5*WL, sbs + 5*32, list, cnt + s, pcnt, pent);
        k_convp<0,1><<<GS,256,0,stream>>>(X,  A, A,       sws + 6*WL, sbs + 6*32, list, cnt + s, pcnt, pent);
        k_convp<0,0><<<GS,256,0,stream>>>(A, HS, nullptr, sws + 7*WL, sbs + 7*32, list, cnt + s, pcnt, pent);

        k_classifier<<<512,256,0,stream>>>(HS, cw0, cb0, cw1, cb1, cw2, cb2,
                                           out + (size_t)s * M_ALL, so);
    }
}